// Round 5
// baseline (1600.752 us; speedup 1.0000x reference)
//
#include <hip/hip_runtime.h>
#include <math.h>

// Problem constants (derived from reference): N=50000 nodes, E=800000 edges,
// H=D=128, G=500 graphs, L=100 seq len, C=10 classes. N == G*L exactly.

#define HD 128

// ---------------------------------------------------------------------------
// K1: histogram of dst -> row_count
__global__ void k_hist(const int* __restrict__ dst, int* __restrict__ cnt, int E) {
    int e = blockIdx.x * blockDim.x + threadIdx.x;
    if (e < E) atomicAdd(&cnt[dst[e]], 1);
}

// ---------------------------------------------------------------------------
// K2: single-block exclusive scan of row_count -> row_ptr (+cursor copy) and
// dis[n] = rsqrt(deg) with deg = row_count + 1 (self loop).
__global__ __launch_bounds__(1024) void k_scan(const int* __restrict__ cnt,
                                               int* __restrict__ row_ptr,
                                               int* __restrict__ cursor,
                                               float* __restrict__ dis,
                                               int n, int E) {
    __shared__ int sums[1024];
    int t = threadIdx.x;
    int chunk = (n + 1023) / 1024;
    int lo = t * chunk, hi = min(lo + chunk, n);
    int s = 0;
    for (int i = lo; i < hi; ++i) s += cnt[i];
    sums[t] = s;
    __syncthreads();
    // Hillis-Steele inclusive scan over 1024 thread sums
    for (int d = 1; d < 1024; d <<= 1) {
        int add = 0;
        if (t >= d) add = sums[t - d];
        __syncthreads();
        sums[t] += add;
        __syncthreads();
    }
    int base = (t == 0) ? 0 : sums[t - 1];
    int run = base;
    for (int i = lo; i < hi; ++i) {
        row_ptr[i] = run;
        cursor[i]  = run;
        int c = cnt[i];
        dis[i] = rsqrtf((float)c + 1.0f);
        run += c;
    }
    if (t == 0) row_ptr[n] = E;
}

// ---------------------------------------------------------------------------
// K3: scatter edges into CSR col array
__global__ void k_fill(const int* __restrict__ src, const int* __restrict__ dst,
                       int* __restrict__ cursor, int* __restrict__ col, int E) {
    int e = blockIdx.x * blockDim.x + threadIdx.x;
    if (e < E) {
        int p = atomicAdd(&cursor[dst[e]], 1);
        col[p] = src[e];
    }
}

// ---------------------------------------------------------------------------
// K4: GEMM  C[M, 128cols-chunk] = A[M,128] * W(chunk)   (f32)
// TRANSW=false: W is [128, 128] row-major, chunk j0=0.     (xw = h @ W)
// TRANSW=true : W is [512, 128] row-major, Wl[k][c]=W[j0+c][k]. (h @ W_ih^T)
// BIAS: add bias[j0+c] + bias2[j0+c] at store.
// block: 256 threads -> 64 rows x 128 cols tile, 8x4 micro-tile per thread.
template <bool TRANSW, bool BIAS>
__global__ __launch_bounds__(256) void k_gemm(const float* __restrict__ A,
                                              const float* __restrict__ W,
                                              const float* __restrict__ bias,
                                              const float* __restrict__ bias2,
                                              float* __restrict__ C,
                                              int M, int ldc) {
    __shared__ float Wl[128][128];  // 64 KiB
    const int j0 = blockIdx.y * 128;

    // stage W chunk into LDS
    if (!TRANSW) {
        int k = threadIdx.x >> 1;
        int half = (threadIdx.x & 1) * 64;
        #pragma unroll
        for (int c4 = 0; c4 < 16; ++c4) {
            float4 v = *(const float4*)&W[k * 128 + half + c4 * 4];
            *(float4*)&Wl[k][half + c4 * 4] = v;
        }
    } else {
        int c = threadIdx.x >> 1;            // col within chunk -> W row j0+c
        int half = (threadIdx.x & 1) * 64;   // k offset
        #pragma unroll
        for (int k4 = 0; k4 < 16; ++k4) {
            float4 v = *(const float4*)&W[(size_t)(j0 + c) * 128 + half + k4 * 4];
            Wl[half + k4 * 4 + 0][c] = v.x;
            Wl[half + k4 * 4 + 1][c] = v.y;
            Wl[half + k4 * 4 + 2][c] = v.z;
            Wl[half + k4 * 4 + 3][c] = v.w;
        }
    }
    __syncthreads();

    const int rg = threadIdx.x >> 5;   // 0..7 row group
    const int ct = threadIdx.x & 31;   // 0..31 col thread (4 cols each)
    const int row0 = blockIdx.x * 64 + rg * 8;

    float acc[8][4];
    #pragma unroll
    for (int i = 0; i < 8; ++i)
        #pragma unroll
        for (int c = 0; c < 4; ++c) acc[i][c] = 0.f;

    for (int kk = 0; kk < 32; ++kk) {
        float4 wv[4];
        #pragma unroll
        for (int x = 0; x < 4; ++x)
            wv[x] = *(const float4*)&Wl[kk * 4 + x][ct * 4];
        #pragma unroll
        for (int i = 0; i < 8; ++i) {
            int r = row0 + i;
            if (r < M) {
                float4 av = *(const float4*)&A[(size_t)r * 128 + kk * 4];
                const float* ap = (const float*)&av;
                #pragma unroll
                for (int x = 0; x < 4; ++x) {
                    const float* wp = (const float*)&wv[x];
                    float a = ap[x];
                    acc[i][0] = fmaf(a, wp[0], acc[i][0]);
                    acc[i][1] = fmaf(a, wp[1], acc[i][1]);
                    acc[i][2] = fmaf(a, wp[2], acc[i][2]);
                    acc[i][3] = fmaf(a, wp[3], acc[i][3]);
                }
            }
        }
    }

    #pragma unroll
    for (int i = 0; i < 8; ++i) {
        int r = row0 + i;
        if (r < M) {
            float4 o;
            o.x = acc[i][0]; o.y = acc[i][1]; o.z = acc[i][2]; o.w = acc[i][3];
            if (BIAS) {
                int jc = j0 + ct * 4;
                o.x += bias[jc + 0] + bias2[jc + 0];
                o.y += bias[jc + 1] + bias2[jc + 1];
                o.z += bias[jc + 2] + bias2[jc + 2];
                o.w += bias[jc + 3] + bias2[jc + 3];
            }
            *(float4*)&C[(size_t)r * ldc + j0 + ct * 4] = o;
        }
    }
}

// ---------------------------------------------------------------------------
// K5: GCN aggregation. One wave (64 lanes) per node; lane handles 2 features.
// out[n][f] = relu( dis[n] * sum_e dis[src_e]*xw[src_e][f]
//                   + xw[n][f]*dis[n]^2 + b[f] )
__global__ __launch_bounds__(256) void k_agg(const float* __restrict__ xw,
                                             const int* __restrict__ row_ptr,
                                             const int* __restrict__ col,
                                             const float* __restrict__ dis,
                                             const float* __restrict__ b,
                                             float* __restrict__ out, int n) {
    int wave = (blockIdx.x * blockDim.x + threadIdx.x) >> 6;
    int lane = threadIdx.x & 63;
    if (wave >= n) return;
    const int node = wave;
    int lo = row_ptr[node];
    int hi = row_ptr[node + 1];
    float ax = 0.f, ay = 0.f;
    #pragma unroll 2
    for (int e = lo; e < hi; ++e) {
        int s = col[e];
        s = __builtin_amdgcn_readfirstlane(s);
        float wsc = __uint_as_float(
            __builtin_amdgcn_readfirstlane(__float_as_uint(dis[s])));
        float2 v = *(const float2*)&xw[(size_t)s * 128 + lane * 2];
        ax = fmaf(wsc, v.x, ax);
        ay = fmaf(wsc, v.y, ay);
    }
    float dn = dis[node];
    float2 self = *(const float2*)&xw[(size_t)node * 128 + lane * 2];
    float2 bb = *(const float2*)&b[lane * 2];
    float ox = fmaxf(fmaf(dn, ax, fmaf(self.x, dn * dn, bb.x)), 0.f);
    float oy = fmaxf(fmaf(dn, ay, fmaf(self.y, dn * dn, bb.y)), 0.f);
    float2 o; o.x = ox; o.y = oy;
    *(float2*)&out[(size_t)node * 128 + lane * 2] = o;
}

// ---------------------------------------------------------------------------
// K6: per-graph LSTM, 100 steps, then final linear to d_out.
// 512 threads = 8 waves; thread j owns gate j (W_hh row j in 128 VGPRs).
// h broadcast: 2 LDS reads/lane + v_readlane per k.
__device__ __forceinline__ float rl(float v, int k) {
    return __uint_as_float(__builtin_amdgcn_readlane(__float_as_uint(v), k));
}
__device__ __forceinline__ float fast_sigmoid(float x) {
    return 1.0f / (1.0f + __expf(-x));
}
__device__ __forceinline__ float fast_tanh(float x) {
    float ax = fabsf(x);
    float e = __expf(2.0f * ax);       // >= 1, inf-safe
    float t = 1.0f - 2.0f / (e + 1.0f);
    return copysignf(t, x);
}

__global__ __launch_bounds__(512) void k_lstm(const float* __restrict__ xgates,
                                              const float* __restrict__ W_hh,
                                              const float* __restrict__ linW,
                                              const float* __restrict__ linb,
                                              float* __restrict__ out,
                                              int seqlen) {
    const int g = blockIdx.x;
    const int j = threadIdx.x;      // 0..511 gate index
    const int lane = j & 63;

    float w[128];
    #pragma unroll
    for (int q = 0; q < 32; ++q) {
        float4 v = *(const float4*)&W_hh[(size_t)j * 128 + q * 4];
        w[q * 4 + 0] = v.x; w[q * 4 + 1] = v.y;
        w[q * 4 + 2] = v.z; w[q * 4 + 3] = v.w;
    }

    __shared__ float h_s[128];
    __shared__ float c_s[128];
    __shared__ float gate_s[512];
    if (j < 128) { h_s[j] = 0.f; c_s[j] = 0.f; }
    __syncthreads();

    const float* xg = xgates + (size_t)g * seqlen * 512;
    float xv = xg[j];  // prefetch t=0

    for (int t = 0; t < seqlen; ++t) {
        float xn = (t + 1 < seqlen) ? xg[(size_t)(t + 1) * 512 + j] : 0.f;
        float h0 = h_s[lane];
        float h1 = h_s[64 + lane];
        float a0 = 0.f, a1 = 0.f, a2 = 0.f, a3 = 0.f;
        #pragma unroll
        for (int k = 0; k < 64; k += 2) {
            a0 = fmaf(rl(h0, k),     w[k],          a0);
            a1 = fmaf(rl(h1, k),     w[64 + k],     a1);
            a2 = fmaf(rl(h0, k + 1), w[k + 1],      a2);
            a3 = fmaf(rl(h1, k + 1), w[64 + k + 1], a3);
        }
        float acc = xv + ((a0 + a2) + (a1 + a3));

        float gv;
        if (j < 256)      gv = fast_sigmoid(acc);  // i (0..127), f (128..255)
        else if (j < 384) gv = fast_tanh(acc);     // g
        else              gv = fast_sigmoid(acc);  // o
        gate_s[j] = gv;
        __syncthreads();
        if (j < 128) {
            float i_ = gate_s[j];
            float f_ = gate_s[128 + j];
            float g_ = gate_s[256 + j];
            float o_ = gate_s[384 + j];
            float c = fmaf(f_, c_s[j], i_ * g_);
            c_s[j] = c;
            h_s[j] = o_ * fast_tanh(c);
        }
        __syncthreads();
        xv = xn;
    }

    // final linear: out[g, c] = sum_k h[k] * linW[k*10 + c] + linb[c]
    if (j < 10) {
        float s = linb[j];
        for (int k = 0; k < 128; ++k) s = fmaf(h_s[k], linW[k * 10 + j], s);
        out[(size_t)g * 10 + j] = s;
    }
}

// ---------------------------------------------------------------------------
extern "C" void kernel_launch(void* const* d_in, const int* in_sizes, int n_in,
                              void* d_out, int out_size, void* d_ws, size_t ws_size,
                              hipStream_t stream) {
    const float* x    = (const float*)d_in[0];
    const int*   ei   = (const int*)d_in[1];
    // d_in[2] = batch (unused: contiguous L nodes per graph -> reshape)
    const float* W1 = (const float*)d_in[3];
    const float* b1 = (const float*)d_in[4];
    const float* W2 = (const float*)d_in[5];
    const float* b2 = (const float*)d_in[6];
    const float* W3 = (const float*)d_in[7];
    const float* b3 = (const float*)d_in[8];
    const float* W4 = (const float*)d_in[9];
    const float* b4 = (const float*)d_in[10];
    const float* W_ih = (const float*)d_in[11];
    const float* W_hh = (const float*)d_in[12];
    const float* b_ih = (const float*)d_in[13];
    const float* b_hh = (const float*)d_in[14];
    const float* linW = (const float*)d_in[15];
    const float* linb = (const float*)d_in[16];
    float* out = (float*)d_out;

    const int N = in_sizes[0] / HD;          // 50000
    const int E = in_sizes[1] / 2;           // 800000
    const int G = out_size / 10;             // 500
    const int L = N / G;                     // 100

    const int* src = ei;
    const int* dst = ei + E;

    // workspace layout (aligned 256B)
    char* p = (char*)d_ws;
    auto alloc = [&](size_t bytes) {
        char* r = p;
        p += (bytes + 255) & ~(size_t)255;
        return r;
    };
    int*   row_count = (int*)alloc((size_t)N * 4);
    int*   row_ptr   = (int*)alloc((size_t)(N + 1) * 4);
    int*   cursor    = (int*)alloc((size_t)N * 4);
    int*   col       = (int*)alloc((size_t)E * 4);
    float* dis       = (float*)alloc((size_t)N * 4);
    float* bufA      = (float*)alloc((size_t)N * HD * 4);   // xw
    float* bufB      = (float*)alloc((size_t)N * HD * 4);   // h
    float* xgates    = (float*)alloc((size_t)N * 512 * 4);
    (void)ws_size;

    // CSR build
    hipMemsetAsync(row_count, 0, (size_t)N * 4, stream);
    int ethreads = 256, eblocks = (E + 255) / 256;
    k_hist<<<eblocks, ethreads, 0, stream>>>(dst, row_count, E);
    k_scan<<<1, 1024, 0, stream>>>(row_count, row_ptr, cursor, dis, N, E);
    k_fill<<<eblocks, ethreads, 0, stream>>>(src, dst, cursor, col, E);

    // 4 GCN layers: xw -> bufA, h -> bufB
    dim3 ggrid((N + 63) / 64, 1);
    int ablocks = (N + 3) / 4;  // 4 waves per 256-thread block, 1 wave/node
    const float* h_in = x;
    const float* Ws[4] = {W1, W2, W3, W4};
    const float* bs[4] = {b1, b2, b3, b4};
    for (int l = 0; l < 4; ++l) {
        k_gemm<false, false><<<ggrid, 256, 0, stream>>>(h_in, Ws[l], nullptr,
                                                        nullptr, bufA, N, HD);
        k_agg<<<ablocks, 256, 0, stream>>>(bufA, row_ptr, col, dis, bs[l],
                                           bufB, N);
        h_in = bufB;
    }

    // xgates = h4 @ W_ih^T + b_ih + b_hh   [N, 512]
    dim3 xgrid((N + 63) / 64, 4);
    k_gemm<true, true><<<xgrid, 256, 0, stream>>>(bufB, W_ih, b_ih, b_hh,
                                                  xgates, N, 512);

    // per-graph LSTM + final linear
    k_lstm<<<G, 512, 0, stream>>>(xgates, W_hh, linW, linb, out, L);
}

// Round 6
// 1109.393 us; speedup vs baseline: 1.4429x; 1.4429x over previous
//
#include <hip/hip_runtime.h>
#include <math.h>

// Problem constants (derived from reference): N=50000 nodes, E=800000 edges,
// H=D=128, G=500 graphs, L=100 seq len, C=10 classes. N == G*L exactly.

#define HD 128

// ---------------------------------------------------------------------------
// K1: histogram of dst -> row_count
__global__ void k_hist(const int* __restrict__ dst, int* __restrict__ cnt, int E) {
    int e = blockIdx.x * blockDim.x + threadIdx.x;
    if (e < E) atomicAdd(&cnt[dst[e]], 1);
}

// ---------------------------------------------------------------------------
// K2: single-block exclusive scan of row_count -> row_ptr (+cursor copy) and
// dis[n] = rsqrt(deg) with deg = row_count + 1 (self loop).
__global__ __launch_bounds__(1024) void k_scan(const int* __restrict__ cnt,
                                               int* __restrict__ row_ptr,
                                               int* __restrict__ cursor,
                                               float* __restrict__ dis,
                                               int n, int E) {
    __shared__ int sums[1024];
    int t = threadIdx.x;
    int chunk = (n + 1023) / 1024;
    int lo = t * chunk, hi = min(lo + chunk, n);
    int s = 0;
    for (int i = lo; i < hi; ++i) s += cnt[i];
    sums[t] = s;
    __syncthreads();
    // Hillis-Steele inclusive scan over 1024 thread sums
    for (int d = 1; d < 1024; d <<= 1) {
        int add = 0;
        if (t >= d) add = sums[t - d];
        __syncthreads();
        sums[t] += add;
        __syncthreads();
    }
    int base = (t == 0) ? 0 : sums[t - 1];
    int run = base;
    for (int i = lo; i < hi; ++i) {
        row_ptr[i] = run;
        cursor[i]  = run;
        int c = cnt[i];
        dis[i] = rsqrtf((float)c + 1.0f);
        run += c;
    }
    if (t == 0) row_ptr[n] = E;
}

// ---------------------------------------------------------------------------
// K3: scatter edges into CSR col array
__global__ void k_fill(const int* __restrict__ src, const int* __restrict__ dst,
                       int* __restrict__ cursor, int* __restrict__ col, int E) {
    int e = blockIdx.x * blockDim.x + threadIdx.x;
    if (e < E) {
        int p = atomicAdd(&cursor[dst[e]], 1);
        col[p] = src[e];
    }
}

// ---------------------------------------------------------------------------
// K4 (v2): LDS-staged tiled GEMM.  C[M, 128-col chunk] = A[M,128] * W(chunk).
// TRANSW=false: W is [128, NC] row-major (layer GEMM, NC=128, blockIdx.y=0).
// TRANSW=true : W is [512, 128] row-major; effective Wl[k][c] = W[j0+c][k]
//               (xgates = h @ W_ih^T, 4 y-blocks of 128 cols).
// 256 threads; output tile 128 rows x 128 cols; 8x8 micro-tile per thread;
// K=128 processed in 4 chunks of 32 staged in LDS.
// LDS: As[128][33] (+1 pad: conflict-free column reads) + Ws[32][128] = 33 KB
//      -> 4 blocks/CU (vs 64KB/2 blocks in v1); A loads now coalesced, once.
template <bool TRANSW, bool BIAS>
__global__ __launch_bounds__(256) void k_gemm(const float* __restrict__ A,
                                              const float* __restrict__ W,
                                              const float* __restrict__ bias,
                                              const float* __restrict__ bias2,
                                              float* __restrict__ C,
                                              int M, int ldc) {
    __shared__ float As[128][33];   // 16.9 KB
    __shared__ float Ws[32][128];   // 16.0 KB
    const int tid  = threadIdx.x;
    const int j0   = blockIdx.y * 128;
    const int row0 = blockIdx.x * 128;

    const int cx = tid & 15;   // col group: cols cx*8 .. cx*8+7
    const int ry = tid >> 4;   // row group: rows ry*8 .. ry*8+7

    float acc[8][8];
    #pragma unroll
    for (int i = 0; i < 8; ++i)
        #pragma unroll
        for (int j = 0; j < 8; ++j) acc[i][j] = 0.f;

    for (int kc = 0; kc < 4; ++kc) {
        // ---- stage A chunk: rows row0..row0+127, k = kc*32..kc*32+31 ----
        {
            int r  = tid >> 1;            // 0..127
            int k0 = (tid & 1) * 16;      // 0 or 16
            int gr = row0 + r;
            if (gr >= M) gr = M - 1;      // clamp: garbage rows never stored
            const float* ap = &A[(size_t)gr * 128 + kc * 32 + k0];
            #pragma unroll
            for (int i = 0; i < 4; ++i) {
                float4 v = *(const float4*)&ap[i * 4];
                As[r][k0 + i * 4 + 0] = v.x;
                As[r][k0 + i * 4 + 1] = v.y;
                As[r][k0 + i * 4 + 2] = v.z;
                As[r][k0 + i * 4 + 3] = v.w;
            }
        }
        // ---- stage W chunk ----
        if (!TRANSW) {
            int k  = tid >> 3;            // 0..31
            int c0 = (tid & 7) * 16;      // 0..112
            const float* wp = &W[(size_t)(kc * 32 + k) * ldc + j0 + c0];
            #pragma unroll
            for (int i = 0; i < 4; ++i)
                *(float4*)&Ws[k][c0 + i * 4] = *(const float4*)&wp[i * 4];
        } else {
            int c  = tid >> 1;            // 0..127  -> W row j0+c
            int k0 = (tid & 1) * 16;      // 0 or 16
            const float* wp = &W[(size_t)(j0 + c) * 128 + kc * 32 + k0];
            #pragma unroll
            for (int i = 0; i < 4; ++i) {
                float4 v = *(const float4*)&wp[i * 4];
                Ws[k0 + i * 4 + 0][c] = v.x;
                Ws[k0 + i * 4 + 1][c] = v.y;
                Ws[k0 + i * 4 + 2][c] = v.z;
                Ws[k0 + i * 4 + 3][c] = v.w;
            }
        }
        __syncthreads();

        // ---- compute: 32 k-steps x 8x8 FMA ----
        #pragma unroll 8
        for (int k = 0; k < 32; ++k) {
            float wv[8];
            *(float4*)&wv[0] = *(const float4*)&Ws[k][cx * 8];
            *(float4*)&wv[4] = *(const float4*)&Ws[k][cx * 8 + 4];
            float av[8];
            #pragma unroll
            for (int i = 0; i < 8; ++i) av[i] = As[ry * 8 + i][k];
            #pragma unroll
            for (int i = 0; i < 8; ++i)
                #pragma unroll
                for (int j = 0; j < 8; ++j)
                    acc[i][j] = fmaf(av[i], wv[j], acc[i][j]);
        }
        __syncthreads();
    }

    // ---- store (+bias) ----
    #pragma unroll
    for (int i = 0; i < 8; ++i) {
        int r = row0 + ry * 8 + i;
        if (r < M) {
            int jc = j0 + cx * 8;
            float4 o0, o1;
            o0.x = acc[i][0]; o0.y = acc[i][1]; o0.z = acc[i][2]; o0.w = acc[i][3];
            o1.x = acc[i][4]; o1.y = acc[i][5]; o1.z = acc[i][6]; o1.w = acc[i][7];
            if (BIAS) {
                o0.x += bias[jc + 0] + bias2[jc + 0];
                o0.y += bias[jc + 1] + bias2[jc + 1];
                o0.z += bias[jc + 2] + bias2[jc + 2];
                o0.w += bias[jc + 3] + bias2[jc + 3];
                o1.x += bias[jc + 4] + bias2[jc + 4];
                o1.y += bias[jc + 5] + bias2[jc + 5];
                o1.z += bias[jc + 6] + bias2[jc + 6];
                o1.w += bias[jc + 7] + bias2[jc + 7];
            }
            *(float4*)&C[(size_t)r * ldc + jc]     = o0;
            *(float4*)&C[(size_t)r * ldc + jc + 4] = o1;
        }
    }
}

// ---------------------------------------------------------------------------
// K5: GCN aggregation. One wave (64 lanes) per node; lane handles 2 features.
// out[n][f] = relu( dis[n] * sum_e dis[src_e]*xw[src_e][f]
//                   + xw[n][f]*dis[n]^2 + b[f] )
__global__ __launch_bounds__(256) void k_agg(const float* __restrict__ xw,
                                             const int* __restrict__ row_ptr,
                                             const int* __restrict__ col,
                                             const float* __restrict__ dis,
                                             const float* __restrict__ b,
                                             float* __restrict__ out, int n) {
    int wave = (blockIdx.x * blockDim.x + threadIdx.x) >> 6;
    int lane = threadIdx.x & 63;
    if (wave >= n) return;
    const int node = wave;
    int lo = row_ptr[node];
    int hi = row_ptr[node + 1];
    float ax = 0.f, ay = 0.f;
    #pragma unroll 2
    for (int e = lo; e < hi; ++e) {
        int s = col[e];
        s = __builtin_amdgcn_readfirstlane(s);
        float wsc = __uint_as_float(
            __builtin_amdgcn_readfirstlane(__float_as_uint(dis[s])));
        float2 v = *(const float2*)&xw[(size_t)s * 128 + lane * 2];
        ax = fmaf(wsc, v.x, ax);
        ay = fmaf(wsc, v.y, ay);
    }
    float dn = dis[node];
    float2 self = *(const float2*)&xw[(size_t)node * 128 + lane * 2];
    float2 bb = *(const float2*)&b[lane * 2];
    float ox = fmaxf(fmaf(dn, ax, fmaf(self.x, dn * dn, bb.x)), 0.f);
    float oy = fmaxf(fmaf(dn, ay, fmaf(self.y, dn * dn, bb.y)), 0.f);
    float2 o; o.x = ox; o.y = oy;
    *(float2*)&out[(size_t)node * 128 + lane * 2] = o;
}

// ---------------------------------------------------------------------------
// K6: per-graph LSTM, 100 steps, then final linear to d_out.
// 512 threads = 8 waves; thread j owns gate j (W_hh row j in 128 VGPRs).
// h broadcast: 2 LDS reads/lane + v_readlane per k.
__device__ __forceinline__ float rl(float v, int k) {
    return __uint_as_float(__builtin_amdgcn_readlane(__float_as_uint(v), k));
}
__device__ __forceinline__ float fast_sigmoid(float x) {
    return 1.0f / (1.0f + __expf(-x));
}
__device__ __forceinline__ float fast_tanh(float x) {
    float ax = fabsf(x);
    float e = __expf(2.0f * ax);       // >= 1, inf-safe
    float t = 1.0f - 2.0f / (e + 1.0f);
    return copysignf(t, x);
}

__global__ __launch_bounds__(512) void k_lstm(const float* __restrict__ xgates,
                                              const float* __restrict__ W_hh,
                                              const float* __restrict__ linW,
                                              const float* __restrict__ linb,
                                              float* __restrict__ out,
                                              int seqlen) {
    const int g = blockIdx.x;
    const int j = threadIdx.x;      // 0..511 gate index
    const int lane = j & 63;

    float w[128];
    #pragma unroll
    for (int q = 0; q < 32; ++q) {
        float4 v = *(const float4*)&W_hh[(size_t)j * 128 + q * 4];
        w[q * 4 + 0] = v.x; w[q * 4 + 1] = v.y;
        w[q * 4 + 2] = v.z; w[q * 4 + 3] = v.w;
    }

    __shared__ float h_s[128];
    __shared__ float c_s[128];
    __shared__ float gate_s[512];
    if (j < 128) { h_s[j] = 0.f; c_s[j] = 0.f; }
    __syncthreads();

    const float* xg = xgates + (size_t)g * seqlen * 512;
    float xv = xg[j];  // prefetch t=0

    for (int t = 0; t < seqlen; ++t) {
        float xn = (t + 1 < seqlen) ? xg[(size_t)(t + 1) * 512 + j] : 0.f;
        float h0 = h_s[lane];
        float h1 = h_s[64 + lane];
        float a0 = 0.f, a1 = 0.f, a2 = 0.f, a3 = 0.f;
        #pragma unroll
        for (int k = 0; k < 64; k += 2) {
            a0 = fmaf(rl(h0, k),     w[k],          a0);
            a1 = fmaf(rl(h1, k),     w[64 + k],     a1);
            a2 = fmaf(rl(h0, k + 1), w[k + 1],      a2);
            a3 = fmaf(rl(h1, k + 1), w[64 + k + 1], a3);
        }
        float acc = xv + ((a0 + a2) + (a1 + a3));

        float gv;
        if (j < 256)      gv = fast_sigmoid(acc);  // i (0..127), f (128..255)
        else if (j < 384) gv = fast_tanh(acc);     // g
        else              gv = fast_sigmoid(acc);  // o
        gate_s[j] = gv;
        __syncthreads();
        if (j < 128) {
            float i_ = gate_s[j];
            float f_ = gate_s[128 + j];
            float g_ = gate_s[256 + j];
            float o_ = gate_s[384 + j];
            float c = fmaf(f_, c_s[j], i_ * g_);
            c_s[j] = c;
            h_s[j] = o_ * fast_tanh(c);
        }
        __syncthreads();
        xv = xn;
    }

    // final linear: out[g, c] = sum_k h[k] * linW[k*10 + c] + linb[c]
    if (j < 10) {
        float s = linb[j];
        for (int k = 0; k < 128; ++k) s = fmaf(h_s[k], linW[k * 10 + j], s);
        out[(size_t)g * 10 + j] = s;
    }
}

// ---------------------------------------------------------------------------
extern "C" void kernel_launch(void* const* d_in, const int* in_sizes, int n_in,
                              void* d_out, int out_size, void* d_ws, size_t ws_size,
                              hipStream_t stream) {
    const float* x    = (const float*)d_in[0];
    const int*   ei   = (const int*)d_in[1];
    // d_in[2] = batch (unused: contiguous L nodes per graph -> reshape)
    const float* W1 = (const float*)d_in[3];
    const float* b1 = (const float*)d_in[4];
    const float* W2 = (const float*)d_in[5];
    const float* b2 = (const float*)d_in[6];
    const float* W3 = (const float*)d_in[7];
    const float* b3 = (const float*)d_in[8];
    const float* W4 = (const float*)d_in[9];
    const float* b4 = (const float*)d_in[10];
    const float* W_ih = (const float*)d_in[11];
    const float* W_hh = (const float*)d_in[12];
    const float* b_ih = (const float*)d_in[13];
    const float* b_hh = (const float*)d_in[14];
    const float* linW = (const float*)d_in[15];
    const float* linb = (const float*)d_in[16];
    float* out = (float*)d_out;

    const int N = in_sizes[0] / HD;          // 50000
    const int E = in_sizes[1] / 2;           // 800000
    const int G = out_size / 10;             // 500
    const int L = N / G;                     // 100

    const int* src = ei;
    const int* dst = ei + E;

    // workspace layout (aligned 256B)
    char* p = (char*)d_ws;
    auto alloc = [&](size_t bytes) {
        char* r = p;
        p += (bytes + 255) & ~(size_t)255;
        return r;
    };
    int*   row_count = (int*)alloc((size_t)N * 4);
    int*   row_ptr   = (int*)alloc((size_t)(N + 1) * 4);
    int*   cursor    = (int*)alloc((size_t)N * 4);
    int*   col       = (int*)alloc((size_t)E * 4);
    float* dis       = (float*)alloc((size_t)N * 4);
    float* bufA      = (float*)alloc((size_t)N * HD * 4);   // xw
    float* bufB      = (float*)alloc((size_t)N * HD * 4);   // h
    float* xgates    = (float*)alloc((size_t)N * 512 * 4);
    (void)ws_size;

    // CSR build
    hipMemsetAsync(row_count, 0, (size_t)N * 4, stream);
    int ethreads = 256, eblocks = (E + 255) / 256;
    k_hist<<<eblocks, ethreads, 0, stream>>>(dst, row_count, E);
    k_scan<<<1, 1024, 0, stream>>>(row_count, row_ptr, cursor, dis, N, E);
    k_fill<<<eblocks, ethreads, 0, stream>>>(src, dst, cursor, col, E);

    // 4 GCN layers: xw -> bufA, h -> bufB
    dim3 ggrid((N + 127) / 128, 1);
    int ablocks = (N + 3) / 4;  // 4 waves per 256-thread block, 1 wave/node
    const float* h_in = x;
    const float* Ws[4] = {W1, W2, W3, W4};
    const float* bs[4] = {b1, b2, b3, b4};
    for (int l = 0; l < 4; ++l) {
        k_gemm<false, false><<<ggrid, 256, 0, stream>>>(h_in, Ws[l], nullptr,
                                                        nullptr, bufA, N, HD);
        k_agg<<<ablocks, 256, 0, stream>>>(bufA, row_ptr, col, dis, bs[l],
                                           bufB, N);
        h_in = bufB;
    }

    // xgates = h4 @ W_ih^T + b_ih + b_hh   [N, 512]
    dim3 xgrid((N + 127) / 128, 4);
    k_gemm<true, true><<<xgrid, 256, 0, stream>>>(bufB, W_ih, b_ih, b_hh,
                                                  xgates, N, 512);

    // per-graph LSTM + final linear
    k_lstm<<<G, 512, 0, stream>>>(xgates, W_hh, linW, linb, out, L);
}